// Round 4
// baseline (206.398 us; speedup 1.0000x reference)
//
#include <hip/hip_runtime.h>
#include <math.h>

#define N_EMB 1024
#define D_EMB 512

// One WAVE (64 lanes) per (b,s) row; 4 rows per 256-thread block.
// Lane i owns elements {c*256 + i*4 + j : c<4, j<4} of the N=1024 row.
// No LDS, no __syncthreads — shuffle-only reductions.
__global__ __launch_bounds__(256) void gumbel_quantize_kernel(
    const float* __restrict__ logits,   // [rows, 1024]
    const float* __restrict__ u,        // [rows, 1024]
    const float* __restrict__ embed,    // [1024, 512]
    float*       __restrict__ zq,       // [rows, 512]
    float*       __restrict__ diff,     // [rows, 1024]
    float*       __restrict__ indf)     // [rows] (int stored as float)
{
    const int lane = threadIdx.x & 63;
    const int wave = threadIdx.x >> 6;
    const int row  = blockIdx.x * 4 + wave;
    const size_t rbase = (size_t)row * N_EMB;

    const float4* lp = (const float4*)(logits + rbase);
    const float4* up = (const float4*)(u      + rbase);

    // Issue all 8 vector loads up front (8 KB in flight per wave).
    float4 l4[4], u4[4];
    #pragma unroll
    for (int c = 0; c < 4; ++c) l4[c] = lp[c * 64 + lane];
    #pragma unroll
    for (int c = 0; c < 4; ++c) u4[c] = up[c * 64 + lane];

    float lv[16];
    #pragma unroll
    for (int c = 0; c < 4; ++c) {
        lv[c*4+0] = l4[c].x; lv[c*4+1] = l4[c].y;
        lv[c*4+2] = l4[c].z; lv[c*4+3] = l4[c].w;
    }

    // ---- per-lane: gumbel-perturbed argmax (libm logf: argmax-critical)
    //      and logit max ----
    float smax = -INFINITY; int sidx = 0;
    float lmax = -INFINITY;
    #pragma unroll
    for (int c = 0; c < 4; ++c) {
        const float us[4] = {u4[c].x, u4[c].y, u4[c].z, u4[c].w};
        #pragma unroll
        for (int j = 0; j < 4; ++j) {
            const float g  = -logf(-logf(us[j]));   // gumbel noise
            const float sc = lv[c*4+j] + g;         // tau == 1.0
            const int idx  = c * 256 + lane * 4 + j;
            if (sc > smax) { smax = sc; sidx = idx; }  // ascending idx order
            lmax = fmaxf(lmax, lv[c*4+j]);
        }
    }

    // ---- wave butterfly: argmax(score) with first-index ties, max(logit) ----
    #pragma unroll
    for (int off = 32; off > 0; off >>= 1) {
        const float v2 = __shfl_xor(smax, off, 64);
        const int   i2 = __shfl_xor(sidx, off, 64);
        if (v2 > smax || (v2 == smax && i2 < sidx)) { smax = v2; sidx = i2; }
        lmax = fmaxf(lmax, __shfl_xor(lmax, off, 64));
    }
    const int   ind = sidx;
    const float m   = lmax;

    // ---- softmax(logits) denominator (hw exp; diff threshold is huge) ----
    float e[16];
    float psum = 0.f;
    #pragma unroll
    for (int j = 0; j < 16; ++j) { e[j] = __expf(lv[j] - m); psum += e[j]; }
    #pragma unroll
    for (int off = 32; off > 0; off >>= 1) psum += __shfl_xor(psum, off, 64);
    const float sum = psum;                 // identical on all lanes
    const float inv = 1.0f / sum;
    // L = ln(N/sum); per-row constant. ln(qy*N) = (lv - m) + L exactly.
    const float L = logf((float)N_EMB * inv);

    // ---- diff = -ln(qy*N)/qy = -((lv-m)+L) * sum / e  (no log, no div) ----
    float4* dp = (float4*)(diff + rbase);
    #pragma unroll
    for (int c = 0; c < 4; ++c) {
        float d[4];
        #pragma unroll
        for (int j = 0; j < 4; ++j) {
            const int k = c * 4 + j;
            d[j] = -((lv[k] - m) + L) * sum * __builtin_amdgcn_rcpf(e[k]);
        }
        dp[c * 64 + lane] = make_float4(d[0], d[1], d[2], d[3]);
    }

    // ---- z_q row = embed[ind] (512 floats, 2 float4 per lane) ----
    const float4* erow = (const float4*)(embed + (size_t)ind * D_EMB);
    float4*       zrow = (float4*)(zq + (size_t)row * D_EMB);
    #pragma unroll
    for (int c = 0; c < 2; ++c) zrow[c * 64 + lane] = erow[c * 64 + lane];

    if (lane == 0) indf[row] = (float)ind;
}

extern "C" void kernel_launch(void* const* d_in, const int* in_sizes, int n_in,
                              void* d_out, int out_size, void* d_ws, size_t ws_size,
                              hipStream_t stream) {
    const float* logits = (const float*)d_in[0];
    const float* u      = (const float*)d_in[1];
    const float* embed  = (const float*)d_in[2];

    const int rows = in_sizes[0] / N_EMB;   // 8*2048 = 16384

    float* out  = (float*)d_out;
    float* zq   = out;                                   // rows*512
    float* diff = zq + (size_t)rows * D_EMB;             // rows*1024
    float* indf = diff + (size_t)rows * N_EMB;           // rows

    gumbel_quantize_kernel<<<rows / 4, 256, 0, stream>>>(logits, u, embed,
                                                         zq, diff, indf);
}